// Round 4
// baseline (362.798 us; speedup 1.0000x reference)
//
#include <hip/hip_runtime.h>
#include <hip/hip_bf16.h>

// ---------- constants (problem-fixed) ----------
#define NNODES 10000
#define NEDGES 80000
#define OBS    128
#define HID    1024
#define ACTD   8
#define NGR    64

typedef __bf16 bf16x8 __attribute__((ext_vector_type(8)));
typedef float  f32x4  __attribute__((ext_vector_type(4)));

__device__ __forceinline__ ushort f2b(float f) {       // f32 -> bf16 (RNE)
    union { float f; unsigned int i; } v; v.f = f;
    unsigned int lsb = (v.i >> 16) & 1u;
    unsigned int r = v.i + 0x7fffu + lsb;
    return (ushort)(r >> 16);
}
__device__ __forceinline__ float b2f(ushort u) {
    union { unsigned int i; float f; } v; v.i = ((unsigned int)u) << 16; return v.f;
}
__device__ __forceinline__ int cix(int v, int hi) {    // clamp index to [0, hi)
    return v < 0 ? 0 : (v >= hi ? hi - 1 : v);
}

// ---------- prep ----------
__global__ void k_init(float* deg, float* zacc, float* pool, float* cnt, int n) {
    int i = blockIdx.x * 256 + threadIdx.x;
    if (i < n) deg[i] = 1.0f;                 // self-loop contributes 1
    if (i < n * ACTD) zacc[i] = 0.0f;
    if (i < NGR * ACTD) pool[i] = 0.0f;
    if (i < NGR) cnt[i] = 0.0f;
}

__global__ void k_count(const int* __restrict__ dst, float* deg, int e) {
    int i = blockIdx.x * 256 + threadIdx.x;
    if (i < e) atomicAdd(&deg[cix(dst[i], NNODES)], 1.0f);
}

__global__ void k_dinv(float* deg, int n) {
    int i = blockIdx.x * 256 + threadIdx.x;
    if (i < n) deg[i] = rsqrtf(fmaxf(deg[i], 1.0f));
}

__global__ void k_coef(const int* __restrict__ src, const int* __restrict__ dst,
                       const float* __restrict__ dinv, float* coef, int e) {
    int i = blockIdx.x * 256 + threadIdx.x;
    if (i < e) coef[i] = dinv[cix(src[i], NNODES)] * dinv[cix(dst[i], NNODES)];
}

// transpose+cast W1 [OBS x HID] f32 -> Wt1 [HID x OBS] bf16
__global__ void k_transpose_cast(const float* __restrict__ in, ushort* __restrict__ out,
                                 int R, int C) {
    __shared__ float tile[32][33];
    int bx = blockIdx.x * 32, by = blockIdx.y * 32;
    int tx = threadIdx.x & 31, ty = threadIdx.x >> 5;   // ty in 0..7
    #pragma unroll
    for (int i = 0; i < 32; i += 8)
        tile[ty + i][tx] = in[(size_t)(by + ty + i) * C + bx + tx];
    __syncthreads();
    #pragma unroll
    for (int i = 0; i < 32; i += 8)
        out[(size_t)(bx + ty + i) * R + by + tx] = f2b(tile[tx][ty + i]);
}

// M2[i][j] = sum_k W2[i][k] * Wl[k][j]   (1024 x 8, f32) — one wave per row i
__global__ void k_m2(const float* __restrict__ W2, const float* __restrict__ Wl,
                     float* __restrict__ M2) {
    int wvid = (blockIdx.x * 256 + threadIdx.x) >> 6;
    int lane = threadIdx.x & 63;
    if (wvid >= HID) return;
    float acc[ACTD];
    #pragma unroll
    for (int j = 0; j < ACTD; ++j) acc[j] = 0.0f;
    for (int it = 0; it < HID / 64; ++it) {
        int k = it * 64 + lane;
        float w2v = W2[(size_t)wvid * HID + k];
        float4 a = *(const float4*)(Wl + (size_t)k * ACTD);
        float4 b = *(const float4*)(Wl + (size_t)k * ACTD + 4);
        acc[0] += w2v * a.x; acc[1] += w2v * a.y; acc[2] += w2v * a.z; acc[3] += w2v * a.w;
        acc[4] += w2v * b.x; acc[5] += w2v * b.y; acc[6] += w2v * b.z; acc[7] += w2v * b.w;
    }
    #pragma unroll
    for (int off = 32; off > 0; off >>= 1)
        #pragma unroll
        for (int j = 0; j < ACTD; ++j)
            acc[j] += __shfl_down(acc[j], off);
    if (lane == 0)
        #pragma unroll
        for (int j = 0; j < ACTD; ++j)
            M2[wvid * ACTD + j] = acc[j];
}

// b2l[j] = sum_k b2[k]*Wl[k][j] + bl[j]  — single wave
__global__ void k_b2l(const float* __restrict__ b2, const float* __restrict__ Wl,
                      const float* __restrict__ bl, float* __restrict__ b2l) {
    int lane = threadIdx.x & 63;
    float acc[ACTD];
    #pragma unroll
    for (int j = 0; j < ACTD; ++j) acc[j] = 0.0f;
    for (int it = 0; it < HID / 64; ++it) {
        int k = it * 64 + lane;
        float bv = b2[k];
        float4 a = *(const float4*)(Wl + (size_t)k * ACTD);
        float4 b = *(const float4*)(Wl + (size_t)k * ACTD + 4);
        acc[0] += bv * a.x; acc[1] += bv * a.y; acc[2] += bv * a.z; acc[3] += bv * a.w;
        acc[4] += bv * b.x; acc[5] += bv * b.y; acc[6] += bv * b.z; acc[7] += bv * b.w;
    }
    #pragma unroll
    for (int off = 32; off > 0; off >>= 1)
        #pragma unroll
        for (int j = 0; j < ACTD; ++j)
            acc[j] += __shfl_down(acc[j], off);
    if (lane == 0)
        #pragma unroll
        for (int j = 0; j < ACTD; ++j)
            b2l[j] = acc[j] + bl[j];
}

// ---------- layer-1 aggregation (on X, 128 dims, all f32) ----------
__global__ void k_aggx_init(const float* __restrict__ x, const float* __restrict__ dinv,
                            float* __restrict__ aggX, int n) {
    int idx = blockIdx.x * 256 + threadIdx.x;          // n*32 total
    if (idx >= n * (OBS / 4)) return;
    int i = idx >> 5, q = idx & 31;
    float d2 = dinv[i] * dinv[i];
    float4 xv = *(const float4*)(x + (size_t)i * OBS + q * 4);
    float4 o = make_float4(xv.x * d2, xv.y * d2, xv.z * d2, xv.w * d2);
    *(float4*)(aggX + (size_t)i * OBS + q * 4) = o;
}

__global__ void k_aggx_edges(const int* __restrict__ src, const int* __restrict__ dst,
                             const float* __restrict__ coef, const float* __restrict__ x,
                             float* __restrict__ aggX, int e) {
    int t = threadIdx.x;
    int ed = blockIdx.x * 8 + (t >> 5);
    if (ed >= e) return;
    int q = t & 31;
    int s = cix(src[ed], NNODES), d = cix(dst[ed], NNODES);
    float c = coef[ed];
    float4 xv = *(const float4*)(x + (size_t)s * OBS + q * 4);
    float* base = aggX + (size_t)d * OBS + q * 4;
    atomicAdd(base + 0, xv.x * c);
    atomicAdd(base + 1, xv.y * c);
    atomicAdd(base + 2, xv.z * c);
    atomicAdd(base + 3, xv.w * c);
}

__global__ void k_cast4(const float* __restrict__ in, ushort* __restrict__ out, int n4) {
    int idx = blockIdx.x * 256 + threadIdx.x;
    if (idx >= n4) return;
    float4 v = *(const float4*)(in + (size_t)idx * 4);
    ushort4 o; o.x = f2b(v.x); o.y = f2b(v.y); o.z = f2b(v.z); o.w = f2b(v.w);
    *(ushort4*)(out + (size_t)idx * 4) = o;
}

// ---------- fused GEMM1 + relu + (tile @ M2) -> zacc ----------
// h1_tile = relu(aggX_bf @ Wt1_tile^T + b1); zacc[row] += h1_tile @ M2[colrange]
// block = 256 threads (4 waves), tile 128x128, K = OBS = 128.
// LDS: As 8K + Bs 8K + stage(bf16, stride 138) 34.5K = 51.5K  (< 64K limit)
__global__ __launch_bounds__(256) void k_gemm1_fused(const ushort* __restrict__ A,
                                                     const ushort* __restrict__ Bt,
                                                     const float* __restrict__ bias,
                                                     const float* __restrict__ M2,
                                                     float* __restrict__ zacc,
                                                     int M) {
    __shared__ ushort As[128 * 32];
    __shared__ ushort Bs[128 * 32];
    __shared__ ushort stage[128 * 138];
    const int t = threadIdx.x;
    const int bm = blockIdx.x, bn = blockIdx.y;
    const int lane = t & 63, wv = t >> 6;
    const int wm = (wv & 1) * 64, wn = (wv >> 1) * 64;
    const int l16 = lane & 15, kg = (lane >> 4) * 8;
    const int r0 = t >> 2;           // 0..63
    const int c0 = (t & 3) << 3;     // 0,8,16,24

    f32x4 acc[4][4];
    #pragma unroll
    for (int i = 0; i < 4; ++i)
        #pragma unroll
        for (int j = 0; j < 4; ++j)
            acc[i][j] = (f32x4){0.f, 0.f, 0.f, 0.f};

    for (int kt = 0; kt < OBS; kt += 32) {
        #pragma unroll
        for (int rd = 0; rd < 2; ++rd) {
            int r = r0 + rd * 64;
            int gr = bm * 128 + r;
            uint4 va = make_uint4(0, 0, 0, 0);
            if (gr < M) va = *(const uint4*)(A + (size_t)gr * OBS + kt + c0);
            *(uint4*)(As + r * 32 + c0) = va;
            int gn = bn * 128 + r;   // HID multiple of 128
            uint4 vb = *(const uint4*)(Bt + (size_t)gn * OBS + kt + c0);
            *(uint4*)(Bs + r * 32 + c0) = vb;
        }
        __syncthreads();
        bf16x8 af[4], bfr[4];
        #pragma unroll
        for (int i = 0; i < 4; ++i)
            af[i] = *(const bf16x8*)(As + (wm + i * 16 + l16) * 32 + kg);
        #pragma unroll
        for (int j = 0; j < 4; ++j)
            bfr[j] = *(const bf16x8*)(Bs + (wn + j * 16 + l16) * 32 + kg);
        #pragma unroll
        for (int i = 0; i < 4; ++i)
            #pragma unroll
            for (int j = 0; j < 4; ++j)
                acc[i][j] = __builtin_amdgcn_mfma_f32_16x16x32_bf16(af[i], bfr[j], acc[i][j], 0, 0, 0);
        __syncthreads();
    }

    // relu(acc + bias) -> stage (bf16), C/D layout: col=lane&15, row=(lane>>4)*4+reg
    #pragma unroll
    for (int i = 0; i < 4; ++i) {
        int rowb = wm + i * 16 + (lane >> 4) * 4;
        #pragma unroll
        for (int j = 0; j < 4; ++j) {
            int col = wn + j * 16 + l16;
            float bj = bias[bn * 128 + col];
            #pragma unroll
            for (int r = 0; r < 4; ++r) {
                float v = acc[i][j][r] + bj;
                stage[(rowb + r) * 138 + col] = f2b(fmaxf(v, 0.0f));
            }
        }
    }
    __syncthreads();

    // per-row reduce: zacc[gr][0..7] += sum_c stage[row][c] * M2[bn*128+c][0..7]
    int row = t & 127, ch = (t >> 7) * 64;
    float p[ACTD];
    #pragma unroll
    for (int j = 0; j < ACTD; ++j) p[j] = 0.0f;
    for (int c = 0; c < 64; ++c) {
        float s = b2f(stage[row * 138 + ch + c]);
        const float* m2p = M2 + (size_t)(bn * 128 + ch + c) * ACTD;
        float4 a = *(const float4*)m2p;
        float4 b = *(const float4*)(m2p + 4);
        p[0] += s * a.x; p[1] += s * a.y; p[2] += s * a.z; p[3] += s * a.w;
        p[4] += s * b.x; p[5] += s * b.y; p[6] += s * b.z; p[7] += s * b.w;
    }
    int gr = bm * 128 + row;
    if (gr < M) {
        #pragma unroll
        for (int j = 0; j < ACTD; ++j)
            atomicAdd(&zacc[(size_t)gr * ACTD + j], p[j]);
    }
}

// ---------- layer-2-collapsed aggregation over ACTD dims ----------
__global__ void k_zagg_init(const float* __restrict__ zacc, const float* __restrict__ dinv,
                            float* __restrict__ zagg, int n) {
    int idx = blockIdx.x * 256 + threadIdx.x;          // n*ACTD
    if (idx >= n * ACTD) return;
    int i = idx >> 3;
    float d = dinv[i];
    zagg[idx] = zacc[idx] * d * d;
}

__global__ void k_zagg_edges(const int* __restrict__ src, const int* __restrict__ dst,
                             const float* __restrict__ coef, const float* __restrict__ zacc,
                             float* __restrict__ zagg, int e) {
    int idx = blockIdx.x * 256 + threadIdx.x;          // e*ACTD
    if (idx >= e * ACTD) return;
    int ed = idx >> 3, j = idx & 7;
    int s = cix(src[ed], NNODES), d = cix(dst[ed], NNODES);
    atomicAdd(&zagg[(size_t)d * ACTD + j], coef[ed] * zacc[(size_t)s * ACTD + j]);
}

// ---------- tanh + global mean pool ----------
__global__ void k_pool(const float* __restrict__ zagg, const float* __restrict__ b2l,
                       const int* __restrict__ batch, float* __restrict__ pool,
                       float* __restrict__ cnt, int n) {
    int idx = blockIdx.x * 256 + threadIdx.x;          // n*ACTD
    if (idx >= n * ACTD) return;
    int i = idx >> 3, j = idx & 7;
    float tz = tanhf(zagg[idx] + b2l[j]);
    int g = cix(batch[i], NGR);
    atomicAdd(&pool[g * ACTD + j], tz);
    if (j == 0) atomicAdd(&cnt[g], 1.0f);
}

__global__ void k_final(const float* __restrict__ pool, const float* __restrict__ cnt,
                        float* __restrict__ out, int total) {
    int i = blockIdx.x * 256 + threadIdx.x;
    if (i < total) out[i] = pool[i] / fmaxf(cnt[i >> 3], 1.0f);
}

// ---------- launch ----------
extern "C" void kernel_launch(void* const* d_in, const int* in_sizes, int n_in,
                              void* d_out, int out_size, void* d_ws, size_t ws_size,
                              hipStream_t stream) {
    const float* x   = (const float*)d_in[0];
    const int*   ei  = (const int*)d_in[1];
    const int*   bat = (const int*)d_in[2];
    const float* W1  = (const float*)d_in[3];
    const float* b1  = (const float*)d_in[4];
    const float* W2  = (const float*)d_in[5];
    const float* b2v = (const float*)d_in[6];
    const float* Wl  = (const float*)d_in[7];
    const float* bl  = (const float*)d_in[8];
    float* out = (float*)d_out;

    const int N = NNODES, E = NEDGES;
    const int* src = ei;
    const int* dst = ei + E;

    // workspace layout — total ~9.0 MB, all region sizes multiple of 256 B
    char* ws = (char*)d_ws;
    size_t off = 0;
    float*  pool   = (float*)(ws + off); off += 2048;                   // 512 f32
    float*  cnt    = (float*)(ws + off); off += 256;                    // 64 f32
    float*  dinv   = (float*)(ws + off); off += 40192;                  // N f32 (deg->dinv)
    float*  coef   = (float*)(ws + off); off += 320000;                 // E f32
    float*  b2l    = (float*)(ws + off); off += 256;                    // 8 f32
    float*  M2     = (float*)(ws + off); off += (size_t)HID * ACTD * 4; // 32768
    ushort* Wt1    = (ushort*)(ws + off); off += (size_t)HID * OBS * 2; // 262144 (bf16)
    float*  zacc   = (float*)(ws + off); off += (size_t)N * ACTD * 4;   // 320000
    float*  zagg   = (float*)(ws + off); off += (size_t)N * ACTD * 4;   // 320000
    float*  aggX_f = (float*)(ws + off); off += (size_t)N * OBS * 4;    // 5120000
    ushort* aggX_bf= (ushort*)(ws + off); off += (size_t)N * OBS * 2;   // 2560000

    // 1. init + degree + dinv + coef
    k_init<<<(N * ACTD + 255) / 256, 256, 0, stream>>>(dinv, zacc, pool, cnt, N);
    k_count<<<(E + 255) / 256, 256, 0, stream>>>(dst, dinv, E);
    k_dinv<<<(N + 255) / 256, 256, 0, stream>>>(dinv, N);
    k_coef<<<(E + 255) / 256, 256, 0, stream>>>(src, dst, dinv, coef, E);

    // 2. weight prep: Wt1 = bf16(W1^T), M2 = W2 @ Wl, b2l = b2 @ Wl + bl
    k_transpose_cast<<<dim3(HID / 32, OBS / 32), 256, 0, stream>>>(W1, Wt1, OBS, HID);
    k_m2<<<(HID * 64 + 255) / 256, 256, 0, stream>>>(W2, Wl, M2);
    k_b2l<<<1, 64, 0, stream>>>(b2v, Wl, bl, b2l);

    // 3. layer-1 aggregation on X (f32 atomics), cast to bf16
    k_aggx_init<<<(N * (OBS / 4) + 255) / 256, 256, 0, stream>>>(x, dinv, aggX_f, N);
    k_aggx_edges<<<E / 8, 256, 0, stream>>>(src, dst, coef, x, aggX_f, E);
    k_cast4<<<(N * (OBS / 4) + 255) / 256, 256, 0, stream>>>(aggX_f, aggX_bf, N * (OBS / 4));

    // 4. fused GEMM1 + relu + @M2 -> zacc   (y = relu(Â X W1 + b1) @ (W2 Wl))
    k_gemm1_fused<<<dim3((N + 127) / 128, HID / 128), 256, 0, stream>>>(
        aggX_bf, Wt1, b1, M2, zacc, N);

    // 5. aggregate y over graph (8 dims), add b2l, tanh, pool
    k_zagg_init<<<(N * ACTD + 255) / 256, 256, 0, stream>>>(zacc, dinv, zagg, N);
    k_zagg_edges<<<(E * ACTD + 255) / 256, 256, 0, stream>>>(src, dst, coef, zacc, zagg, E);
    k_pool<<<(N * ACTD + 255) / 256, 256, 0, stream>>>(zagg, b2l, bat, pool, cnt, N);
    k_final<<<2, 256, 0, stream>>>(pool, cnt, out, NGR * ACTD);
}

// Round 5
// 201.130 us; speedup vs baseline: 1.8038x; 1.8038x over previous
//
#include <hip/hip_runtime.h>
#include <hip/hip_bf16.h>

// ---------- constants (problem-fixed) ----------
#define NNODES 10000
#define NEDGES 80000
#define OBS    128
#define HID    1024
#define ACTD   8
#define NGR    64

typedef __bf16 bf16x8 __attribute__((ext_vector_type(8)));
typedef float  f32x4  __attribute__((ext_vector_type(4)));

__device__ __forceinline__ ushort f2b(float f) {       // f32 -> bf16 (RNE)
    union { float f; unsigned int i; } v; v.f = f;
    unsigned int lsb = (v.i >> 16) & 1u;
    unsigned int r = v.i + 0x7fffu + lsb;
    return (ushort)(r >> 16);
}
__device__ __forceinline__ float b2f(ushort u) {
    union { unsigned int i; float f; } v; v.i = ((unsigned int)u) << 16; return v.f;
}
__device__ __forceinline__ int cix(int v, int hi) {    // clamp index to [0, hi)
    return v < 0 ? 0 : (v >= hi ? hi - 1 : v);
}

// ---------- init: zero accumulators ----------
__global__ void k_init(int* degi, float* zacc, float* pool, float* cnt, int n) {
    int i = blockIdx.x * 256 + threadIdx.x;
    if (i < n) degi[i] = 0;
    if (i < n * ACTD) zacc[i] = 0.0f;
    if (i < NGR * ACTD) pool[i] = 0.0f;
    if (i < NGR) cnt[i] = 0.0f;
}

__global__ void k_count(const int* __restrict__ dst, int* degi, int e) {
    int i = blockIdx.x * 256 + threadIdx.x;
    if (i < e) atomicAdd(&degi[cix(dst[i], NNODES)], 1);
}

__global__ void k_dinv(const int* __restrict__ degi, float* dinv, int n) {
    int i = blockIdx.x * 256 + threadIdx.x;
    if (i < n) dinv[i] = rsqrtf((float)(degi[i] + 1));   // +1 self-loop
}

// single-block exclusive prefix scan over degi -> rowptr (N+1), cursor copy
__global__ __launch_bounds__(1024) void k_scan(const int* __restrict__ degi,
                                               int* rowptr, int* cursor) {
    __shared__ int sums[1024];
    int t = threadIdx.x;
    int base = t * 10;                                   // 10240 >= NNODES
    int local[10];
    int s = 0;
    #pragma unroll
    for (int k = 0; k < 10; ++k) {
        int v = (base + k < NNODES) ? degi[base + k] : 0;
        local[k] = s; s += v;
    }
    sums[t] = s;
    __syncthreads();
    int own = s;
    for (int off = 1; off < 1024; off <<= 1) {
        int v = (t >= off) ? sums[t - off] : 0;
        __syncthreads();
        sums[t] += v;
        __syncthreads();
    }
    int excl = sums[t] - own;
    #pragma unroll
    for (int k = 0; k < 10; ++k) {
        int i = base + k;
        if (i < NNODES) { rowptr[i] = excl + local[k]; cursor[i] = excl + local[k]; }
    }
    if (t == 1023) rowptr[NNODES] = sums[1023];
}

// bucket edges by dst: sorted src + coef
__global__ void k_fill(const int* __restrict__ src, const int* __restrict__ dst,
                       const float* __restrict__ dinv, int* cursor,
                       int* __restrict__ esrc, float* __restrict__ coefs, int e) {
    int i = blockIdx.x * 256 + threadIdx.x;
    if (i >= e) return;
    int s = cix(src[i], NNODES), d = cix(dst[i], NNODES);
    int pos = atomicAdd(&cursor[d], 1);
    esrc[pos] = s;
    coefs[pos] = dinv[s] * dinv[d];
}

// transpose+cast W1 [OBS x HID] f32 -> Wt1 [HID x OBS] bf16
__global__ void k_transpose_cast(const float* __restrict__ in, ushort* __restrict__ out,
                                 int R, int C) {
    __shared__ float tile[32][33];
    int bx = blockIdx.x * 32, by = blockIdx.y * 32;
    int tx = threadIdx.x & 31, ty = threadIdx.x >> 5;
    #pragma unroll
    for (int i = 0; i < 32; i += 8)
        tile[ty + i][tx] = in[(size_t)(by + ty + i) * C + bx + tx];
    __syncthreads();
    #pragma unroll
    for (int i = 0; i < 32; i += 8)
        out[(size_t)(bx + ty + i) * R + by + tx] = f2b(tile[tx][ty + i]);
}

// M2bf[i][j] = bf16( sum_k W2[i][k] * Wl[k][j] )   (1024 x 8) — one wave per row
__global__ void k_m2(const float* __restrict__ W2, const float* __restrict__ Wl,
                     ushort* __restrict__ M2bf) {
    int wvid = (blockIdx.x * 256 + threadIdx.x) >> 6;
    int lane = threadIdx.x & 63;
    if (wvid >= HID) return;
    float acc[ACTD];
    #pragma unroll
    for (int j = 0; j < ACTD; ++j) acc[j] = 0.0f;
    for (int it = 0; it < HID / 64; ++it) {
        int k = it * 64 + lane;
        float w2v = W2[(size_t)wvid * HID + k];
        float4 a = *(const float4*)(Wl + (size_t)k * ACTD);
        float4 b = *(const float4*)(Wl + (size_t)k * ACTD + 4);
        acc[0] += w2v * a.x; acc[1] += w2v * a.y; acc[2] += w2v * a.z; acc[3] += w2v * a.w;
        acc[4] += w2v * b.x; acc[5] += w2v * b.y; acc[6] += w2v * b.z; acc[7] += w2v * b.w;
    }
    #pragma unroll
    for (int off = 32; off > 0; off >>= 1)
        #pragma unroll
        for (int j = 0; j < ACTD; ++j)
            acc[j] += __shfl_down(acc[j], off);
    if (lane == 0)
        #pragma unroll
        for (int j = 0; j < ACTD; ++j)
            M2bf[wvid * ACTD + j] = f2b(acc[j]);
}

// b2l[j] = sum_k b2[k]*Wl[k][j] + bl[j]  — single wave
__global__ void k_b2l(const float* __restrict__ b2, const float* __restrict__ Wl,
                      const float* __restrict__ bl, float* __restrict__ b2l) {
    int lane = threadIdx.x & 63;
    float acc[ACTD];
    #pragma unroll
    for (int j = 0; j < ACTD; ++j) acc[j] = 0.0f;
    for (int it = 0; it < HID / 64; ++it) {
        int k = it * 64 + lane;
        float bv = b2[k];
        float4 a = *(const float4*)(Wl + (size_t)k * ACTD);
        float4 b = *(const float4*)(Wl + (size_t)k * ACTD + 4);
        acc[0] += bv * a.x; acc[1] += bv * a.y; acc[2] += bv * a.z; acc[3] += bv * a.w;
        acc[4] += bv * b.x; acc[5] += bv * b.y; acc[6] += bv * b.z; acc[7] += bv * b.w;
    }
    #pragma unroll
    for (int off = 32; off > 0; off >>= 1)
        #pragma unroll
        for (int j = 0; j < ACTD; ++j)
            acc[j] += __shfl_down(acc[j], off);
    if (lane == 0)
        #pragma unroll
        for (int j = 0; j < ACTD; ++j)
            b2l[j] = acc[j] + bl[j];
}

// ---------- layer-1 aggregation: CSR gather, one wave per node ----------
// aggbf[i] = bf16( x[i]*dinv[i]^2 + sum_{e in in(i)} coefs[e]*x[esrc[e]] )
__global__ void k_aggx(const float* __restrict__ x, const float* __restrict__ dinv,
                       const int* __restrict__ rowptr, const int* __restrict__ esrc,
                       const float* __restrict__ coefs, ushort* __restrict__ aggbf, int n) {
    int wv = (blockIdx.x * 256 + threadIdx.x) >> 6;
    int lane = threadIdx.x & 63;
    if (wv >= n) return;
    float d = dinv[wv], d2 = d * d;
    float2 xv = *(const float2*)(x + (size_t)wv * OBS + lane * 2);
    float v0 = xv.x * d2, v1 = xv.y * d2;
    int e0 = rowptr[wv], e1 = rowptr[wv + 1];
    for (int e = e0; e < e1; ++e) {                      // wave-uniform loop
        int s = esrc[e];
        float c = coefs[e];
        float2 sv = *(const float2*)(x + (size_t)s * OBS + lane * 2);
        v0 += sv.x * c; v1 += sv.y * c;
    }
    ushort2 o; o.x = f2b(v0); o.y = f2b(v1);
    *(ushort2*)(aggbf + (size_t)wv * OBS + lane * 2) = o;
}

// ---------- fused GEMM1 + relu + MFMA epilogue (@M2) -> zacc ----------
// block 256 (4 waves), tile 128x128, K=OBS=128.
// LDS union: [As 4096h | Bs 4096h] overlapped by stage(128x136h), + M2t(16x128h).
__global__ __launch_bounds__(256) void k_gemm1_fused(const ushort* __restrict__ A,
                                                     const ushort* __restrict__ Bt,
                                                     const float* __restrict__ bias,
                                                     const ushort* __restrict__ M2bf,
                                                     float* __restrict__ zacc,
                                                     int M) {
    __shared__ ushort buf[128 * 136 + 16 * 128];         // 38912 B
    ushort* As    = buf;                                 // halves [0, 4096)
    ushort* Bs    = buf + 4096;                          // halves [4096, 8192)
    ushort* stage = buf;                                 // halves [0, 17408) after K-loop
    ushort* M2t   = buf + 128 * 136;                     // halves [17408, 19456)

    const int t = threadIdx.x;
    const int bm = blockIdx.x, bn = blockIdx.y;
    const int lane = t & 63, wv = t >> 6;
    const int wm = (wv & 1) * 64, wn = (wv >> 1) * 64;
    const int l16 = lane & 15, kg = (lane >> 4) * 8;
    const int r0 = t >> 2;
    const int c0 = (t & 3) << 3;

    // stage M2 chunk into LDS transposed: M2t[j][k], j=0..15 (8 real + 8 zero)
    if (t < 128) {
        ushort4 a = *(const ushort4*)(M2bf + (size_t)(bn * 128 + t) * ACTD);
        ushort4 b = *(const ushort4*)(M2bf + (size_t)(bn * 128 + t) * ACTD + 4);
        M2t[0 * 128 + t] = a.x; M2t[1 * 128 + t] = a.y;
        M2t[2 * 128 + t] = a.z; M2t[3 * 128 + t] = a.w;
        M2t[4 * 128 + t] = b.x; M2t[5 * 128 + t] = b.y;
        M2t[6 * 128 + t] = b.z; M2t[7 * 128 + t] = b.w;
        #pragma unroll
        for (int j = 8; j < 16; ++j) M2t[j * 128 + t] = 0;
    }

    f32x4 acc[4][4];
    #pragma unroll
    for (int i = 0; i < 4; ++i)
        #pragma unroll
        for (int j = 0; j < 4; ++j)
            acc[i][j] = (f32x4){0.f, 0.f, 0.f, 0.f};

    for (int kt = 0; kt < OBS; kt += 32) {
        if (kt) __syncthreads();
        #pragma unroll
        for (int rd = 0; rd < 2; ++rd) {
            int r = r0 + rd * 64;
            int gr = bm * 128 + r;
            uint4 va = make_uint4(0, 0, 0, 0);
            if (gr < M) va = *(const uint4*)(A + (size_t)gr * OBS + kt + c0);
            *(uint4*)(As + r * 32 + c0) = va;
            int gn = bn * 128 + r;
            uint4 vb = *(const uint4*)(Bt + (size_t)gn * OBS + kt + c0);
            *(uint4*)(Bs + r * 32 + c0) = vb;
        }
        __syncthreads();
        bf16x8 af[4], bfr[4];
        #pragma unroll
        for (int i = 0; i < 4; ++i)
            af[i] = *(const bf16x8*)(As + (wm + i * 16 + l16) * 32 + kg);
        #pragma unroll
        for (int j = 0; j < 4; ++j)
            bfr[j] = *(const bf16x8*)(Bs + (wn + j * 16 + l16) * 32 + kg);
        #pragma unroll
        for (int i = 0; i < 4; ++i)
            #pragma unroll
            for (int j = 0; j < 4; ++j)
                acc[i][j] = __builtin_amdgcn_mfma_f32_16x16x32_bf16(af[i], bfr[j], acc[i][j], 0, 0, 0);
    }
    __syncthreads();                                     // As/Bs dead; stage takes over

    // relu(acc + bias) -> stage bf16; C/D layout: col=lane&15, row=(lane>>4)*4+reg
    #pragma unroll
    for (int i = 0; i < 4; ++i) {
        int rowb = wm + i * 16 + (lane >> 4) * 4;
        #pragma unroll
        for (int j = 0; j < 4; ++j) {
            int col = wn + j * 16 + l16;
            float bj = bias[bn * 128 + col];
            #pragma unroll
            for (int r = 0; r < 4; ++r)
                stage[(rowb + r) * 136 + col] = f2b(fmaxf(acc[i][j][r] + bj, 0.0f));
        }
    }
    __syncthreads();

    // MFMA epilogue: z[32 rows x 16 cols] per wave = stage_strip @ M2t^T
    #pragma unroll
    for (int st = 0; st < 2; ++st) {
        int row0 = wv * 32 + st * 16;
        f32x4 z = (f32x4){0.f, 0.f, 0.f, 0.f};
        #pragma unroll
        for (int kt = 0; kt < 128; kt += 32) {
            bf16x8 a = *(const bf16x8*)(stage + (row0 + l16) * 136 + kt + kg);
            bf16x8 b = *(const bf16x8*)(M2t + l16 * 128 + kt + kg);
            z = __builtin_amdgcn_mfma_f32_16x16x32_bf16(a, b, z, 0, 0, 0);
        }
        if (l16 < ACTD) {
            int rowb = bm * 128 + row0 + (lane >> 4) * 4;
            #pragma unroll
            for (int r = 0; r < 4; ++r)
                if (rowb + r < M)
                    atomicAdd(&zacc[(size_t)(rowb + r) * ACTD + l16], z[r]);
        }
    }
}

// ---------- layer-2-collapsed aggregation (gather) + tanh + pool ----------
__global__ void k_zfinal(const float* __restrict__ zacc, const float* __restrict__ dinv,
                         const int* __restrict__ rowptr, const int* __restrict__ esrc,
                         const float* __restrict__ coefs, const float* __restrict__ b2l,
                         const int* __restrict__ batch, float* __restrict__ pool,
                         float* __restrict__ cnt, int n) {
    int idx = blockIdx.x * 256 + threadIdx.x;            // n*ACTD
    if (idx >= n * ACTD) return;
    int i = idx >> 3, j = idx & 7;
    float d = dinv[i];
    float v = zacc[idx] * d * d;
    int e0 = rowptr[i], e1 = rowptr[i + 1];
    for (int e = e0; e < e1; ++e)
        v += coefs[e] * zacc[(size_t)esrc[e] * ACTD + j];
    float tz = tanhf(v + b2l[j]);
    int g = cix(batch[i], NGR);
    atomicAdd(&pool[g * ACTD + j], tz);
    if (j == 0) atomicAdd(&cnt[g], 1.0f);
}

__global__ void k_final(const float* __restrict__ pool, const float* __restrict__ cnt,
                        float* __restrict__ out, int total) {
    int i = blockIdx.x * 256 + threadIdx.x;
    if (i < total) out[i] = pool[i] / fmaxf(cnt[i >> 3], 1.0f);
}

// ---------- launch ----------
extern "C" void kernel_launch(void* const* d_in, const int* in_sizes, int n_in,
                              void* d_out, int out_size, void* d_ws, size_t ws_size,
                              hipStream_t stream) {
    const float* x   = (const float*)d_in[0];
    const int*   ei  = (const int*)d_in[1];
    const int*   bat = (const int*)d_in[2];
    const float* W1  = (const float*)d_in[3];
    const float* b1  = (const float*)d_in[4];
    const float* W2  = (const float*)d_in[5];
    const float* b2v = (const float*)d_in[6];
    const float* Wl  = (const float*)d_in[7];
    const float* bl  = (const float*)d_in[8];
    float* out = (float*)d_out;

    const int N = NNODES, E = NEDGES;
    const int* src = ei;
    const int* dst = ei + E;

    // workspace layout — ~4.6 MB total
    char* ws = (char*)d_ws;
    size_t off = 0;
    float*  pool   = (float*)(ws + off); off += 2048;
    float*  cnt    = (float*)(ws + off); off += 256;
    float*  dinv   = (float*)(ws + off); off += 40192;                  // N f32
    int*    degi   = (int*)(ws + off);   off += 40192;                  // N i32
    int*    rowptr = (int*)(ws + off);   off += 40448;                  // N+1 i32
    int*    cursor = (int*)(ws + off);   off += 40192;                  // N i32
    int*    esrc   = (int*)(ws + off);   off += (size_t)E * 4;          // 320000
    float*  coefs  = (float*)(ws + off); off += (size_t)E * 4;          // 320000
    float*  b2l    = (float*)(ws + off); off += 256;
    ushort* M2bf   = (ushort*)(ws + off); off += (size_t)HID * ACTD * 2; // 16384
    ushort* Wt1    = (ushort*)(ws + off); off += (size_t)HID * OBS * 2;  // 262144
    float*  zacc   = (float*)(ws + off); off += (size_t)N * ACTD * 4;    // 320000
    ushort* aggbf  = (ushort*)(ws + off); off += (size_t)N * OBS * 2;    // 2560000

    // 1. degree + dinv + CSR build
    k_init<<<(N * ACTD + 255) / 256, 256, 0, stream>>>(degi, zacc, pool, cnt, N);
    k_count<<<(E + 255) / 256, 256, 0, stream>>>(dst, degi, E);
    k_dinv<<<(N + 255) / 256, 256, 0, stream>>>(degi, dinv, N);
    k_scan<<<1, 1024, 0, stream>>>(degi, rowptr, cursor);
    k_fill<<<(E + 255) / 256, 256, 0, stream>>>(src, dst, dinv, cursor, esrc, coefs, E);

    // 2. weight prep
    k_transpose_cast<<<dim3(HID / 32, OBS / 32), 256, 0, stream>>>(W1, Wt1, OBS, HID);
    k_m2<<<(HID * 64 + 255) / 256, 256, 0, stream>>>(W2, Wl, M2bf);
    k_b2l<<<1, 64, 0, stream>>>(b2v, Wl, bl, b2l);

    // 3. layer-1 aggregation (gather) -> bf16
    k_aggx<<<(N * 64 + 255) / 256, 256, 0, stream>>>(x, dinv, rowptr, esrc, coefs, aggbf, N);

    // 4. fused GEMM1 + relu + @M2 -> zacc
    k_gemm1_fused<<<dim3((N + 127) / 128, HID / 128), 256, 0, stream>>>(
        aggbf, Wt1, b1, M2bf, zacc, N);

    // 5. aggregate z (gather), tanh, pool, finalize
    k_zfinal<<<(N * ACTD + 255) / 256, 256, 0, stream>>>(
        zacc, dinv, rowptr, esrc, coefs, b2l, bat, pool, cnt, N);
    k_final<<<2, 256, 0, stream>>>(pool, cnt, out, NGR * ACTD);
}